// Round 1
// baseline (90.299 us; speedup 1.0000x reference)
//
#include <hip/hip_runtime.h>

// ---------------------------------------------------------------------------
// Adapter: LayerNorm(2048) -> down(64) -> ReLU -> up(2048), 16384 tokens fp32.
// Strategy: fold LN into the down-proj so x is read ONCE:
//   down[n] = rstd*( dot(wg[n],x) - mu*s[n] ) + c[n],  wg = w_down*gamma (bf16)
//   s[n] = sum_d wg[n,d],  c[n] = sum_d w_down[n,d]*beta[d] + b_down[n]
// GEMMs run on bf16 MFMA (16x16x32); stats (sum,sumsq) accumulate in the same
// pass over x. Memory-bound target ~43us (268MB @ 6.3TB/s).
// ---------------------------------------------------------------------------

typedef __attribute__((ext_vector_type(8))) short short8;   // 8 x bf16
typedef __attribute__((ext_vector_type(4))) float f32x4;

#define D_MODEL 2048
#define BNECK   64
#define N_ROWS  16384
#define EPS     1e-5f

__device__ inline short f2bf(float f) {
    unsigned int u = __builtin_bit_cast(unsigned int, f);
    unsigned int r = (u + 0x7fffu + ((u >> 16) & 1u)) >> 16;   // RNE
    return (short)r;
}
__device__ inline float bf2f(short s) {
    unsigned int u = ((unsigned int)(unsigned short)s) << 16;
    return __builtin_bit_cast(float, u);
}

// ---------------------------------------------------------------------------
// Prep: wg = bf16(w_down*gamma) [64x2048], s[n]=sum(wg[n,:]) (bf16-rounded),
// c[n]=sum(w_down[n,:]*beta)+b_down[n], wupb = bf16(w_up) [2048x64].
// ---------------------------------------------------------------------------
__global__ __launch_bounds__(256) void prep_kernel(
    const float* __restrict__ w_down, const float* __restrict__ gamma,
    const float* __restrict__ beta,   const float* __restrict__ b_down,
    const float* __restrict__ w_up,
    short* __restrict__ wg, short* __restrict__ wupb,
    float* __restrict__ s_out, float* __restrict__ c_out)
{
    __shared__ float rs[4], rc[4];
    int b = blockIdx.x;
    if (b < BNECK) {
        int n = b;
        float ps = 0.f, pc = 0.f;
        for (int d = threadIdx.x; d < D_MODEL; d += 256) {
            float wv  = w_down[n * D_MODEL + d];
            short h   = f2bf(wv * gamma[d]);
            wg[n * D_MODEL + d] = h;
            ps += bf2f(h);                       // consistent with bf16 dot
            pc  = fmaf(wv, beta[d], pc);
        }
        for (int o = 32; o > 0; o >>= 1) {
            ps += __shfl_down(ps, o, 64);
            pc += __shfl_down(pc, o, 64);
        }
        int wid = threadIdx.x >> 6, lane = threadIdx.x & 63;
        if (lane == 0) { rs[wid] = ps; rc[wid] = pc; }
        __syncthreads();
        if (threadIdx.x == 0) {
            s_out[n] = rs[0] + rs[1] + rs[2] + rs[3];
            c_out[n] = rc[0] + rc[1] + rc[2] + rc[3] + b_down[n];
        }
    } else {
        // blocks 64..127 convert w_up (2048x64) to bf16
        for (int i = (b - BNECK) * 256 + threadIdx.x; i < D_MODEL * BNECK;
             i += 64 * 256)
            wupb[i] = f2bf(w_up[i]);
    }
}

// ---------------------------------------------------------------------------
// Main fused kernel. 256 blocks x 256 threads; each wave owns 16 rows.
// ---------------------------------------------------------------------------
__global__ __launch_bounds__(256) void adapter_kernel(
    const float* __restrict__ x,    const float* __restrict__ b_up,
    const short* __restrict__ wg,   const short* __restrict__ wup,
    const float* __restrict__ s_v,  const float* __restrict__ c_v,
    float* __restrict__ out)
{
    __shared__ __align__(16) char dlds[4][2048];   // per-wave 16x64 bf16 tile

    const int wid  = threadIdx.x >> 6;
    const int lane = threadIdx.x & 63;
    const int r    = lane & 15;        // A-row / B-col within fragment
    const int g    = lane >> 4;        // k-group
    const int row0 = blockIdx.x * 64 + wid * 16;

    const float* xr  = x  + (size_t)(row0 + r) * D_MODEL + g * 8;
    const short* wgl = wg + r * D_MODEL + g * 8;

    f32x4 acc[4];
#pragma unroll
    for (int nf = 0; nf < 4; ++nf) acc[nf] = (f32x4){0.f, 0.f, 0.f, 0.f};
    float sum = 0.f, sq = 0.f;

    // ---- down-GEMM over K=2048 + LN stats in the same pass -----------------
#pragma unroll 2
    for (int kb = 0; kb < D_MODEL; kb += 32) {
        f32x4 xa = *(const f32x4*)(xr + kb);
        f32x4 xb = *(const f32x4*)(xr + kb + 4);

        sum += ((xa.x + xa.y) + (xa.z + xa.w)) +
               ((xb.x + xb.y) + (xb.z + xb.w));
        sq = fmaf(xa.x, xa.x, sq); sq = fmaf(xa.y, xa.y, sq);
        sq = fmaf(xa.z, xa.z, sq); sq = fmaf(xa.w, xa.w, sq);
        sq = fmaf(xb.x, xb.x, sq); sq = fmaf(xb.y, xb.y, sq);
        sq = fmaf(xb.z, xb.z, sq); sq = fmaf(xb.w, xb.w, sq);

        short8 af;
        af[0] = f2bf(xa.x); af[1] = f2bf(xa.y); af[2] = f2bf(xa.z); af[3] = f2bf(xa.w);
        af[4] = f2bf(xb.x); af[5] = f2bf(xb.y); af[6] = f2bf(xb.z); af[7] = f2bf(xb.w);

        short8 b0 = *(const short8*)(wgl + kb);
        short8 b1 = *(const short8*)(wgl + 16 * D_MODEL + kb);
        short8 b2 = *(const short8*)(wgl + 32 * D_MODEL + kb);
        short8 b3 = *(const short8*)(wgl + 48 * D_MODEL + kb);
        acc[0] = __builtin_amdgcn_mfma_f32_16x16x32_bf16(af, b0, acc[0], 0, 0, 0);
        acc[1] = __builtin_amdgcn_mfma_f32_16x16x32_bf16(af, b1, acc[1], 0, 0, 0);
        acc[2] = __builtin_amdgcn_mfma_f32_16x16x32_bf16(af, b2, acc[2], 0, 0, 0);
        acc[3] = __builtin_amdgcn_mfma_f32_16x16x32_bf16(af, b3, acc[3], 0, 0, 0);
    }

    // ---- LN stats: reduce across the 4 k-groups of each row ---------------
    sum += __shfl_xor(sum, 16, 64); sum += __shfl_xor(sum, 32, 64);
    sq  += __shfl_xor(sq, 16, 64);  sq  += __shfl_xor(sq, 32, 64);
    float mu_r   = sum * (1.f / D_MODEL);
    float var    = sq * (1.f / D_MODEL) - mu_r * mu_r;
    float rstd_r = rsqrtf(var + EPS);

    // lane holds stats for row r; D-frag rows are g*4+reg -> broadcast
    float mu_m[4], rs_m[4];
#pragma unroll
    for (int reg = 0; reg < 4; ++reg) {
        int m = g * 4 + reg;
        mu_m[reg] = __shfl(mu_r, m, 64);
        rs_m[reg] = __shfl(rstd_r, m, 64);
    }

    // ---- fix-up + ReLU, stash 16x64 bf16 tile in LDS (XOR-swizzled) -------
    char* myl = dlds[wid];
#pragma unroll
    for (int nf = 0; nf < 4; ++nf) {
        int   n  = nf * 16 + r;           // bottleneck index (D col)
        float sn = s_v[n], cn = c_v[n];
#pragma unroll
        for (int reg = 0; reg < 4; ++reg) {
            int   m = g * 4 + reg;        // row within 16-row tile
            float v = fmaf(rs_m[reg], acc[nf][reg] - mu_m[reg] * sn, cn);
            v = fmaxf(v, 0.f);
            int off = ((m * 64 + n) * 2) ^ ((m & 7) << 4);
            *(short*)(myl + off) = f2bf(v);
        }
    }
    asm volatile("s_waitcnt lgkmcnt(0)" ::: "memory");

    // ---- up-GEMM: M=16, N=2048, K=64 --------------------------------------
    short8 aup0 = *(const short8*)(myl + ((r * 128 +  0 + g * 16) ^ ((r & 7) << 4)));
    short8 aup1 = *(const short8*)(myl + ((r * 128 + 64 + g * 16) ^ ((r & 7) << 4)));

    const short* wupl = wup + r * BNECK + g * 8;
    float* outr = out + (size_t)row0 * D_MODEL;

#pragma unroll 4
    for (int nf2 = 0; nf2 < 128; ++nf2) {
        int d = nf2 * 16 + r;
        short8 b0 = *(const short8*)(wupl + nf2 * 16 * BNECK);
        short8 b1 = *(const short8*)(wupl + nf2 * 16 * BNECK + 32);
        f32x4 o = (f32x4){0.f, 0.f, 0.f, 0.f};
        o = __builtin_amdgcn_mfma_f32_16x16x32_bf16(aup0, b0, o, 0, 0, 0);
        o = __builtin_amdgcn_mfma_f32_16x16x32_bf16(aup1, b1, o, 0, 0, 0);
        float bu = b_up[d];
#pragma unroll
        for (int reg = 0; reg < 4; ++reg)
            outr[(size_t)(g * 4 + reg) * D_MODEL + d] = o[reg] + bu;
    }
}

extern "C" void kernel_launch(void* const* d_in, const int* in_sizes, int n_in,
                              void* d_out, int out_size, void* d_ws, size_t ws_size,
                              hipStream_t stream) {
    const float* x      = (const float*)d_in[0];
    const float* gamma  = (const float*)d_in[1];
    const float* beta   = (const float*)d_in[2];
    const float* w_down = (const float*)d_in[3];
    const float* b_down = (const float*)d_in[4];
    const float* w_up   = (const float*)d_in[5];
    const float* b_up   = (const float*)d_in[6];
    float* out = (float*)d_out;

    char* ws = (char*)d_ws;
    short* wg   = (short*)ws;                    // 64*2048*2   = 262144 B
    short* wupb = (short*)(ws + 262144);         // 2048*64*2   = 262144 B
    float* s_v  = (float*)(ws + 524288);         // 256 B
    float* c_v  = (float*)(ws + 524544);         // 256 B

    prep_kernel<<<128, 256, 0, stream>>>(w_down, gamma, beta, b_down, w_up,
                                         wg, wupb, s_v, c_v);
    adapter_kernel<<<256, 256, 0, stream>>>(x, b_up, wg, wupb, s_v, c_v, out);
}